// Round 9
// baseline (366.931 us; speedup 1.0000x reference)
//
#include <hip/hip_runtime.h>

#define D_ 160
#define H_ 192
#define W_ 160
#define HW_ (H_*W_)
#define V_ (D_*H_*W_)
#define NTOT (2*V_)

#define TW 32
#define TH 16
#define DC 40
#define NCHUNK (D_/DC)    // 4
#define RH 24             // TH + 8 halo
#define TWP 33            // ws stride pad
#define NBLOCKS (5*12*NCHUNK*2)   // 480

// 16B zero page for OOB load sources (L2-resident after first touch).
__device__ __align__(64) float zpad_g[4] = {0.f, 0.f, 0.f, 0.f};

// RTNE f32x2 -> packed bf16x2 and back (validated: absmax 0.0 through R16).
__device__ inline unsigned pack_bf2(float a, float b) {
  unsigned ua = __float_as_uint(a), ub = __float_as_uint(b);
  ua += 0x7fffu + ((ua >> 16) & 1u);
  ub += 0x7fffu + ((ub >> 16) & 1u);
  return (ua & 0xffff0000u) | (ub >> 16);
}
__device__ inline float2 unpack_bf2(unsigned u) {
  return make_float2(__uint_as_float(u & 0xffff0000u),
                     __uint_as_float(u << 16));
}

// ---------------------------------------------------------------------------
// Fused separable 9x9x9 box filter + NCC.
// R14: WIN 86->71us: merged C+B region, ONE barrier/step, DC=40 (DMA->LDS
//      staging, depth-2 spacing via vmcnt(2)). LDS-pipe-bound (~69%).
// R15: FAILED: depth-2 REG prefetch w/ 48+12 regs + 18-unroll -> 535MB spill.
// R16: NEUTRAL-HURT (87us): depth-1 reg prefetch, 84 VGPR, no spill, LDS tax
//      gone (-280cyc/step) BUT ~390cyc/step of EXPOSED HBM latency: issue->
//      consume gap ~1 C-phase < 900cyc loaded latency. Spacing, not traffic.
// R17: depth-2 on the register path at R16's register bill + 24:
//      two parity sets (p = t&1, static under 18-unroll; 54=3x18).
//      issue(t): slice c0-4+t -> set[p]   (t in [0,48), after B consumed it)
//      B(t):     consume set[p] = slice t-2 -> W-sums -> ws[t&1], t in [2,50)
//      Cover issue(t)->consume B(t+2): bar + C + B + bar + C ~ 2 steps
//      ~3500cyc >> HBM latency. WAR (consume then overwrite same set) is
//      safe: in-order issue per wave, reads complete at issue.
//      C unchanged from R16. LDS = ws only (31680B). Barrier lgkm-only.
// Spill canary: WRITE_SIZE must stay ~KB (R10/R12/R15 all died by scratch).
// ---------------------------------------------------------------------------
__global__ __launch_bounds__(256, 3) void ncc_fused(const float* __restrict__ I,
                                                    const float* __restrict__ J,
                                                    float* __restrict__ bsum) {
  __shared__ float4 ws4[2][RH][TWP];    // 25344 B W-sums f0-3, double-buffered
  __shared__ float  ws1[2][RH][TWP];    //  6336 B W-sums f4,   double-buffered
                                        // total 31680 B

  const int tid = threadIdx.x;
  const int w0 = blockIdx.x * TW;               // 5
  const int h0 = blockIdx.y * TH;               // 12
  const int c0 = (blockIdx.z % NCHUNK) * DC;    // 4 chunks
  const int batch = blockIdx.z / NCHUNK;        // 2

  const float* Ib = I + (size_t)batch * V_;
  const float* Jb = J + (size_t)batch * V_;
  const float* zp = zpad_g;

  // B mapping (tid < 192): wave w -> rows 8w+(tid&7), run (tid>>3)&7.
  // (row varies with LOW lane bits -> ws4-write bank starts spread.)
  const int br = ((tid >> 6) << 3) | (tid & 7);
  const int brun = (tid >> 3) & 7;
  const int bc = brun * 4;

  // B global window: row hr = h0-4+br, cols cb..cb+11 (cb quad-aligned).
  // OOB is exactly quad-granular (W_, w0, cb all multiples of 4).
  const int hr = h0 - 4 + br;
  const int cb = w0 - 4 + 4 * brun;
  const bool rowok = ((unsigned)hr < (unsigned)H_) && (tid < 192);
  const bool q0ok = rowok && ((unsigned)(cb)     < (unsigned)W_);
  const bool q1ok = rowok && ((unsigned)(cb + 4) < (unsigned)W_);
  const bool q2ok = rowok && ((unsigned)(cb + 8) < (unsigned)W_);
  const int hr_ok = rowok ? hr : 0;
  const float* rbI = Ib + (size_t)hr_ok * W_;   // row base (2 regs)
  const float* rbJ = Jb + (size_t)hr_ok * W_;   // row base (2 regs)

  // C mapping: col tx, output rows hb, hb+1
  const int tx = tid & 31;
  const int hb = (tid >> 5) * 2;

  unsigned ring[5][9];
  float sum0[5], sum1[5];
#pragma unroll
  for (int f = 0; f < 5; ++f) {
    sum0[f] = 0.f; sum1[f] = 0.f;
#pragma unroll
    for (int k = 0; k < 9; ++k) ring[f][k] = 0u;
  }

  // Two prefetch register sets, parity-selected (static under 18-unroll).
  float4 rI0[2], rI1[2], rI2[2], rJ0[2], rJ1[2], rJ2[2];
  const float4 z4 = make_float4(0.f, 0.f, 0.f, 0.f);
  rI0[0] = rI0[1] = rI1[0] = rI1[1] = rI2[0] = rI2[1] = z4;
  rJ0[0] = rJ0[1] = rJ1[0] = rJ1[1] = rJ2[0] = rJ2[1] = z4;

  float local = 0.f;

#pragma unroll 1
  for (int tb = 0; tb < 54; tb += 18) {
#pragma unroll
    for (int u = 0; u < 18; ++u) {
      const int t = tb + u;                 // 0..53; phases self-guard
      const int u9 = (u < 9) ? u : u - 9;   // t % 9 (ring slot, static)
      const int p  = u & 1;                 // t % 2 (reg set,  static)

      // ---- top-of-step barrier: B(t-1)'s ws writes visible to C(t);
      //      C(t) reads ws[(t+1)&1], B(t) writes ws[t&1] -> no intra hazard.
      //      lgkm-only: in-flight register prefetches span the barrier.
      if (t >= 3 && t < DC + 11) {
        asm volatile("s_waitcnt lgkmcnt(0)" ::: "memory");
        __builtin_amdgcn_s_barrier();
      }

      // ---- C: H-dir 9-sums of ws[(t+1)&1] (= slice t-3) + bf16 D-ring ----
      if (t >= 3 && t < DC + 11) {
        const float4 (*W4r)[TWP] = ws4[(t + 1) & 1];
        const float  (*W1r)[TWP] = ws1[(t + 1) & 1];
        float v0 = 0.f, v1 = 0.f, v2 = 0.f, v3 = 0.f, v4 = 0.f;
        float4 k4; float k1v;
#pragma unroll
        for (int k = 0; k < 9; ++k) {
          const float4 a4 = W4r[hb + k][tx];
          const float  a1f = W1r[hb + k][tx];
          if (k == 0) { k4 = a4; k1v = a1f; }
          v0 += a4.x; v1 += a4.y; v2 += a4.z; v3 += a4.w; v4 += a1f;
        }
        const float4 t4 = W4r[hb + 9][tx];
        const float  t1 = W1r[hb + 9][tx];
        float hv0[5], hv1[5];
        hv0[0] = v0; hv0[1] = v1; hv0[2] = v2; hv0[3] = v3; hv0[4] = v4;
        hv1[0] = v0 + t4.x - k4.x;
        hv1[1] = v1 + t4.y - k4.y;
        hv1[2] = v2 + t4.z - k4.z;
        hv1[3] = v3 + t4.w - k4.w;
        hv1[4] = v4 + t1   - k1v;

#pragma unroll
        for (int f = 0; f < 5; ++f) {
          const float2 old = unpack_bf2(ring[f][u9]);
          sum0[f] += hv0[f] - old.x;
          sum1[f] += hv1[f] - old.y;
          ring[f][u9] = pack_bf2(hv0[f], hv1[f]);
        }

        if (t >= 11) {
          const float inv = 1.f / 729.f;
          const float cx0 = sum0[4] - sum0[0] * sum0[1] * inv;
          const float iv0 = sum0[2] - sum0[0] * sum0[0] * inv;
          const float jv0 = sum0[3] - sum0[1] * sum0[1] * inv;
          local += cx0 * cx0 * __builtin_amdgcn_rcpf(iv0 * jv0 + 1e-5f);
          const float cx1 = sum1[4] - sum1[0] * sum1[1] * inv;
          const float iv1 = sum1[2] - sum1[0] * sum1[0] * inv;
          const float jv1 = sum1[3] - sum1[1] * sum1[1] * inv;
          local += cx1 * cx1 * __builtin_amdgcn_rcpf(iv1 * jv1 + 1e-5f);
        }
      }

      // ---- B consume: set[p] (= slice t-2, issued at t-2) -> ws[t&1] ----
      if (t >= 2 && t < DC + 10 && tid < 192) {
        const float4 A0 = rI0[p], A1 = rI1[p], A2 = rI2[p];
        const float4 B0 = rJ0[p], B1 = rJ1[p], B2 = rJ2[p];
        const float ai[12] = {A0.x,A0.y,A0.z,A0.w, A1.x,A1.y,A1.z,A1.w,
                              A2.x,A2.y,A2.z,A2.w};
        const float aj[12] = {B0.x,B0.y,B0.z,B0.w, B1.x,B1.y,B1.z,B1.w,
                              B2.x,B2.y,B2.z,B2.w};
        float4* W4 = ws4[t & 1][br];
        float*  W1 = ws1[t & 1][br];
        float s0 = 0.f, s1 = 0.f, s2 = 0.f, s3 = 0.f, s4 = 0.f;
#pragma unroll
        for (int k = 0; k < 9; ++k) {
          const float a = ai[k], b = aj[k];
          s0 += a; s1 += b; s2 += a * a; s3 += b * b; s4 += a * b;
        }
        W4[bc] = make_float4(s0, s1, s2, s3);
        W1[bc] = s4;
#pragma unroll
        for (int m = 1; m < 4; ++m) {
          const float ea = ai[8 + m], eb = aj[8 + m];
          const float la = ai[m - 1], lb = aj[m - 1];
          s0 += ea - la;
          s1 += eb - lb;
          s2 += ea * ea - la * la;
          s3 += eb * eb - lb * lb;
          s4 += ea * eb - la * lb;
          W4[bc + m] = make_float4(s0, s1, s2, s3);
          W1[bc + m] = s4;
        }
      }

      // ---- issue: slice s = c0-4+t -> set[p] (consumed by B(t+2)).
      //      WAR vs consume above: in-order per wave -> safe. ----
      if (t < DC + 8 && tid < 192) {
        const int s = c0 - 4 + t;
        const bool sin = (unsigned)s < (unsigned)D_;
        const size_t so = (size_t)(sin ? s : 0) * HW_;
        const float* pI = rbI + so + cb;
        const float* pJ = rbJ + so + cb;
        rI0[p] = *(const float4*)((sin && q0ok) ? pI       : zp);
        rI1[p] = *(const float4*)((sin && q1ok) ? (pI + 4) : zp);
        rI2[p] = *(const float4*)((sin && q2ok) ? (pI + 8) : zp);
        rJ0[p] = *(const float4*)((sin && q0ok) ? pJ       : zp);
        rJ1[p] = *(const float4*)((sin && q1ok) ? (pJ + 4) : zp);
        rJ2[p] = *(const float4*)((sin && q2ok) ? (pJ + 8) : zp);
      }
    }
  }

  // ---- block reduction (reuse ws4 space) -> per-block partial ----
  __syncthreads();   // C(50)'s ws reads consumed before the space is reused
  float* red = (float*)&ws4[0][0][0];
  red[tid] = local;
  __syncthreads();
  for (int s2 = 128; s2 > 0; s2 >>= 1) {
    if (tid < s2) red[tid] += red[tid + s2];
    __syncthreads();
  }
  if (tid == 0) {
    const int bid = (blockIdx.z * 12 + blockIdx.y) * 5 + blockIdx.x;
    bsum[bid] = red[0];
  }
}

__global__ __launch_bounds__(256) void finalize_k(const float* __restrict__ bsum,
                                                  float* __restrict__ out) {
  __shared__ double red[256];
  double d = 0.0;
  for (int i = threadIdx.x; i < NBLOCKS; i += 256) d += (double)bsum[i];
  red[threadIdx.x] = d;
  __syncthreads();
  for (int s = 128; s > 0; s >>= 1) {
    if (threadIdx.x < s) red[threadIdx.x] += red[threadIdx.x + s];
    __syncthreads();
  }
  if (threadIdx.x == 0) out[0] = (float)(-red[0] / (double)NTOT);
}

extern "C" void kernel_launch(void* const* d_in, const int* in_sizes, int n_in,
                              void* d_out, int out_size, void* d_ws, size_t ws_size,
                              hipStream_t stream) {
  const float* I = (const float*)d_in[0];   // y_true
  const float* J = (const float*)d_in[1];   // y_pred
  float* out = (float*)d_out;
  float* bsum = (float*)d_ws;               // 480 floats

  dim3 grid(W_ / TW, H_ / TH, NCHUNK * 2);  // 5 x 12 x 8 = 480 blocks
  ncc_fused<<<grid, 256, 0, stream>>>(I, J, bsum);
  finalize_k<<<1, 256, 0, stream>>>(bsum, out);
}

// Round 10
// 164.369 us; speedup vs baseline: 2.2324x; 2.2324x over previous
//
#include <hip/hip_runtime.h>

#define D_ 160
#define H_ 192
#define W_ 160
#define HW_ (H_*W_)
#define V_ (D_*H_*W_)
#define NTOT (2*V_)

#define TW 32
#define TH 16
#define DC 20
#define NCHUNK (D_/DC)    // 8
#define RH 24             // TH + 8 halo
#define TWP 33            // ws stride pad
#define NBLOCKS (5*12*NCHUNK*2)   // 960

// 16B zero page for OOB load sources (L2-resident after first touch).
__device__ __align__(64) float zpad_g[4] = {0.f, 0.f, 0.f, 0.f};

// RTNE f32x2 -> packed bf16x2 and back (validated: absmax 0.0 through R16).
__device__ inline unsigned pack_bf2(float a, float b) {
  unsigned ua = __float_as_uint(a), ub = __float_as_uint(b);
  ua += 0x7fffu + ((ua >> 16) & 1u);
  ub += 0x7fffu + ((ub >> 16) & 1u);
  return (ua & 0xffff0000u) | (ub >> 16);
}
__device__ inline float2 unpack_bf2(unsigned u) {
  return make_float2(__uint_as_float(u & 0xffff0000u),
                     __uint_as_float(u << 16));
}

// ---------------------------------------------------------------------------
// Fused separable 9x9x9 box filter + NCC.
// R14: WIN 71us: merged C+B region, ONE barrier/step, DMA staging depth-2.
// R15/R17: FAILED (292-380us): 18-wide unroll + parity ARRAYS never fully
//      unroll -> runtime index -> arrays live in SCRATCH (rule #20), not a
//      true reg-pressure spill (both report VGPR=84!). Depth-2 reg prefetch
//      is structurally unavailable. R12 was likely the same disease (ringB).
// R16: 87us, CLEAN (84 VGPR, 15KB WRITE): depth-1 reg prefetch, LDS tax gone,
//      but ~390cyc/step exposed HBM latency -- only 2 blocks/CU of TLP
//      because grid=480 was the residency limiter (LDS/VGPR allow 5).
// R18: R16 structure, DC 40->20: grid 960 -> max-loaded CU holds 4 blocks
//      (4x4 waves, 4x31.7KB LDS, 84 VGPR all fit) -> 4-way TLP hides the
//      load-wait behind other blocks' C/B compute. +18% total steps (halo
//      re-staging) traded for 2x concurrency at 45% utilization.
// Pipeline (u = t%9 static; DC=20):
//   top-bar(t): lgkmcnt(0) + s_barrier            t in [3,31)
//   C(t):   ws[(t+1)&1] (slice t-3 out) H-sums + D-ring, t in [3,31), emit>=11
//   B(t):   consume regs (slice c0-6+t) -> W-sums -> ws[t&1], t in [2,30)
//   issue(t): slice c0-5+t -> regs (feeds B(t+1)),  t in [1,29)
// Spill canary: WRITE_SIZE must stay ~KB; VGPR=84 + huge WRITE = rule #20.
// ---------------------------------------------------------------------------
__global__ __launch_bounds__(256, 3) void ncc_fused(const float* __restrict__ I,
                                                    const float* __restrict__ J,
                                                    float* __restrict__ bsum) {
  __shared__ float4 ws4[2][RH][TWP];    // 25344 B W-sums f0-3, double-buffered
  __shared__ float  ws1[2][RH][TWP];    //  6336 B W-sums f4,   double-buffered
                                        // total 31680 B -> 4-5 blocks/CU

  const int tid = threadIdx.x;
  const int w0 = blockIdx.x * TW;               // 5
  const int h0 = blockIdx.y * TH;               // 12
  const int c0 = (blockIdx.z % NCHUNK) * DC;    // 8 chunks
  const int batch = blockIdx.z / NCHUNK;        // 2

  const float* Ib = I + (size_t)batch * V_;
  const float* Jb = J + (size_t)batch * V_;
  const float* zp = zpad_g;

  // B mapping (tid < 192): wave w -> rows 8w+(tid&7), run (tid>>3)&7.
  // (row varies with LOW lane bits -> ws4-write bank starts spread.)
  const int br = ((tid >> 6) << 3) | (tid & 7);
  const int brun = (tid >> 3) & 7;
  const int bc = brun * 4;

  // B global window: row hr = h0-4+br, cols cb..cb+11 (cb quad-aligned).
  // OOB is exactly quad-granular (W_, w0, cb all multiples of 4).
  const int hr = h0 - 4 + br;
  const int cb = w0 - 4 + 4 * brun;
  const bool rowok = ((unsigned)hr < (unsigned)H_) && (tid < 192);
  const bool q0ok = rowok && ((unsigned)(cb)     < (unsigned)W_);
  const bool q1ok = rowok && ((unsigned)(cb + 4) < (unsigned)W_);
  const bool q2ok = rowok && ((unsigned)(cb + 8) < (unsigned)W_);
  const int hr_ok = rowok ? hr : 0;
  const float* rbI = Ib + (size_t)hr_ok * W_;   // row base (2 regs)
  const float* rbJ = Jb + (size_t)hr_ok * W_;   // row base (2 regs)

  // C mapping: col tx, output rows hb, hb+1
  const int tx = tid & 31;
  const int hb = (tid >> 5) * 2;

  unsigned ring[5][9];
  float sum0[5], sum1[5];
#pragma unroll
  for (int f = 0; f < 5; ++f) {
    sum0[f] = 0.f; sum1[f] = 0.f;
#pragma unroll
    for (int k = 0; k < 9; ++k) ring[f][k] = 0u;
  }

  // Single prefetch register set (depth-1, NAMED scalars -- no arrays).
  float4 rI0, rI1, rI2, rJ0, rJ1, rJ2;

  float local = 0.f;

#pragma unroll 1
  for (int tb = 0; tb < 36; tb += 9) {
#pragma unroll
    for (int u = 0; u < 9; ++u) {
      const int t = tb + u;              // 0..35; phases self-guard (31..35 idle)

      // ---- top-of-step barrier: B(t-1)'s ws writes visible to C(t);
      //      C(t) reads ws[(t+1)&1], B(t) writes ws[t&1] -> no intra hazard.
      //      lgkm-only: in-flight register prefetches span the barrier.
      if (t >= 3 && t < DC + 11) {
        asm volatile("s_waitcnt lgkmcnt(0)" ::: "memory");
        __builtin_amdgcn_s_barrier();
      }

      // ---- C: H-dir 9-sums of ws[(t+1)&1] (= slice t-3) + bf16 D-ring ----
      if (t >= 3 && t < DC + 11) {
        const float4 (*W4r)[TWP] = ws4[(t + 1) & 1];
        const float  (*W1r)[TWP] = ws1[(t + 1) & 1];
        float v0 = 0.f, v1 = 0.f, v2 = 0.f, v3 = 0.f, v4 = 0.f;
        float4 k4; float k1v;
#pragma unroll
        for (int k = 0; k < 9; ++k) {
          const float4 a4 = W4r[hb + k][tx];
          const float  a1f = W1r[hb + k][tx];
          if (k == 0) { k4 = a4; k1v = a1f; }
          v0 += a4.x; v1 += a4.y; v2 += a4.z; v3 += a4.w; v4 += a1f;
        }
        const float4 t4 = W4r[hb + 9][tx];
        const float  t1 = W1r[hb + 9][tx];
        float hv0[5], hv1[5];
        hv0[0] = v0; hv0[1] = v1; hv0[2] = v2; hv0[3] = v3; hv0[4] = v4;
        hv1[0] = v0 + t4.x - k4.x;
        hv1[1] = v1 + t4.y - k4.y;
        hv1[2] = v2 + t4.z - k4.z;
        hv1[3] = v3 + t4.w - k4.w;
        hv1[4] = v4 + t1   - k1v;

#pragma unroll
        for (int f = 0; f < 5; ++f) {
          const float2 old = unpack_bf2(ring[f][u]);
          sum0[f] += hv0[f] - old.x;
          sum1[f] += hv1[f] - old.y;
          ring[f][u] = pack_bf2(hv0[f], hv1[f]);
        }

        if (t >= 11) {
          const float inv = 1.f / 729.f;
          const float cx0 = sum0[4] - sum0[0] * sum0[1] * inv;
          const float iv0 = sum0[2] - sum0[0] * sum0[0] * inv;
          const float jv0 = sum0[3] - sum0[1] * sum0[1] * inv;
          local += cx0 * cx0 * __builtin_amdgcn_rcpf(iv0 * jv0 + 1e-5f);
          const float cx1 = sum1[4] - sum1[0] * sum1[1] * inv;
          const float iv1 = sum1[2] - sum1[0] * sum1[0] * inv;
          const float jv1 = sum1[3] - sum1[1] * sum1[1] * inv;
          local += cx1 * cx1 * __builtin_amdgcn_rcpf(iv1 * jv1 + 1e-5f);
        }
      }

      // ---- B consume: W-dir 9-sums (global slice c0-6+t) -> ws[t&1] ----
      if (t >= 2 && t < DC + 10 && tid < 192) {
        const float4 A0 = rI0, A1 = rI1, A2 = rI2;
        const float4 B0 = rJ0, B1 = rJ1, B2 = rJ2;
        const float ai[12] = {A0.x,A0.y,A0.z,A0.w, A1.x,A1.y,A1.z,A1.w,
                              A2.x,A2.y,A2.z,A2.w};
        const float aj[12] = {B0.x,B0.y,B0.z,B0.w, B1.x,B1.y,B1.z,B1.w,
                              B2.x,B2.y,B2.z,B2.w};
        float4* W4 = ws4[t & 1][br];
        float*  W1 = ws1[t & 1][br];
        float s0 = 0.f, s1 = 0.f, s2 = 0.f, s3 = 0.f, s4 = 0.f;
#pragma unroll
        for (int k = 0; k < 9; ++k) {
          const float a = ai[k], b = aj[k];
          s0 += a; s1 += b; s2 += a * a; s3 += b * b; s4 += a * b;
        }
        W4[bc] = make_float4(s0, s1, s2, s3);
        W1[bc] = s4;
#pragma unroll
        for (int m = 1; m < 4; ++m) {
          const float ea = ai[8 + m], eb = aj[8 + m];
          const float la = ai[m - 1], lb = aj[m - 1];
          s0 += ea - la;
          s1 += eb - lb;
          s2 += ea * ea - la * la;
          s3 += eb * eb - lb * lb;
          s4 += ea * eb - la * lb;
          W4[bc + m] = make_float4(s0, s1, s2, s3);
          W1[bc + m] = s4;
        }
      }

      // ---- issue: global slice s = c0-5+t -> regs (feeds B(t+1)).
      //      WAR on the same regs: in-order per wave, consume above reads
      //      them (operand read at issue) before these loads rewrite. ----
      if (t >= 1 && t < DC + 9 && tid < 192) {
        const int s = c0 - 5 + t;
        const bool sin = (unsigned)s < (unsigned)D_;
        const size_t so = (size_t)(sin ? s : 0) * HW_;
        const float* pI = rbI + so + cb;
        const float* pJ = rbJ + so + cb;
        rI0 = *(const float4*)((sin && q0ok) ? pI       : zp);
        rI1 = *(const float4*)((sin && q1ok) ? (pI + 4) : zp);
        rI2 = *(const float4*)((sin && q2ok) ? (pI + 8) : zp);
        rJ0 = *(const float4*)((sin && q0ok) ? pJ       : zp);
        rJ1 = *(const float4*)((sin && q1ok) ? (pJ + 4) : zp);
        rJ2 = *(const float4*)((sin && q2ok) ? (pJ + 8) : zp);
      }
    }
  }

  // ---- block reduction (reuse ws4 space) -> per-block partial ----
  __syncthreads();   // C(30)'s ws reads consumed before the space is reused
  float* red = (float*)&ws4[0][0][0];
  red[tid] = local;
  __syncthreads();
  for (int s2 = 128; s2 > 0; s2 >>= 1) {
    if (tid < s2) red[tid] += red[tid + s2];
    __syncthreads();
  }
  if (tid == 0) {
    const int bid = (blockIdx.z * 12 + blockIdx.y) * 5 + blockIdx.x;
    bsum[bid] = red[0];
  }
}

__global__ __launch_bounds__(256) void finalize_k(const float* __restrict__ bsum,
                                                  float* __restrict__ out) {
  __shared__ double red[256];
  double d = 0.0;
  for (int i = threadIdx.x; i < NBLOCKS; i += 256) d += (double)bsum[i];
  red[threadIdx.x] = d;
  __syncthreads();
  for (int s = 128; s > 0; s >>= 1) {
    if (threadIdx.x < s) red[threadIdx.x] += red[threadIdx.x + s];
    __syncthreads();
  }
  if (threadIdx.x == 0) out[0] = (float)(-red[0] / (double)NTOT);
}

extern "C" void kernel_launch(void* const* d_in, const int* in_sizes, int n_in,
                              void* d_out, int out_size, void* d_ws, size_t ws_size,
                              hipStream_t stream) {
  const float* I = (const float*)d_in[0];   // y_true
  const float* J = (const float*)d_in[1];   // y_pred
  float* out = (float*)d_out;
  float* bsum = (float*)d_ws;               // 960 floats

  dim3 grid(W_ / TW, H_ / TH, NCHUNK * 2);  // 5 x 12 x 16 = 960 blocks
  ncc_fused<<<grid, 256, 0, stream>>>(I, J, bsum);
  finalize_k<<<1, 256, 0, stream>>>(bsum, out);
}

// Round 11
// 147.935 us; speedup vs baseline: 2.4804x; 1.1111x over previous
//
#include <hip/hip_runtime.h>

#define D_ 160
#define H_ 192
#define W_ 160
#define HW_ (H_*W_)
#define V_ (D_*H_*W_)
#define NTOT (2*V_)

#define TW 32
#define TH 16
#define DC 40
#define NCHUNK (D_/DC)    // 4
#define RH 24             // TH + 8 halo
#define TWP 33            // ws stride pad
#define NBLOCKS (5*12*NCHUNK*2)   // 480

// 16B zero page for boundary/out-of-range DMA sources (L2-resident; keeps
// per-wave global_load_lds issue count uniform so counted vmcnt is sound).
__device__ __align__(64) float zpad_g[4] = {0.f, 0.f, 0.f, 0.f};

// 16B global->LDS DMA. LDS dest = wave-uniform base + lane*16 (m97/m104).
#define GLD16(gp, lp) \
  __builtin_amdgcn_global_load_lds( \
      (const __attribute__((address_space(1))) unsigned int*)(const void*)(gp), \
      (__attribute__((address_space(3))) unsigned int*)(void*)(lp), 16, 0, 0)

// RTNE f32x2 -> packed bf16x2 and back (validated: absmax 0.0 through R18).
__device__ inline unsigned pack_bf2(float a, float b) {
  unsigned ua = __float_as_uint(a), ub = __float_as_uint(b);
  ua += 0x7fffu + ((ua >> 16) & 1u);
  ub += 0x7fffu + ((ub >> 16) & 1u);
  return (ua & 0xffff0000u) | (ub >> 16);
}
__device__ inline float2 unpack_bf2(unsigned u) {
  return make_float2(__uint_as_float(u & 0xffff0000u),
                     __uint_as_float(u << 16));
}

// ---------------------------------------------------------------------------
// Fused separable 9x9x9 box filter + NCC.
// R14 (BEST, 71us): merged C+B region, ONE barrier/step, DMA->LDS staging
//      with depth-2 spacing (vmcnt(2)), DC=40, ws double-buffered.
// R15-R18 (reg-prefetch branch, 87-380us): EXHAUSTED. Depth-1 exposes ~390
//      cyc/step of HBM latency (consumer waits on its OWN vmcnt); depth-2
//      needs parity arrays -> rule-#20 scratch (VGPR=84 + half-GB WRITE_SIZE,
//      twice); TLP x2 (R18) moved nothing. DMA staging decouples consumer
//      from producer -- structurally better. Reverted to R14.
// R19: R14 + XCD-aware block swizzle. FETCH 167MB = 2.13x ideal (W/H halo
//      re-reads). lid=(bid%8)*60+bid/8 (bijective, 480=8x60): each XCD owns
//      one (chunk,batch) slab of 60 tiles; slab live-slice set ~0.74MB << 4MB
//      XCD-L2 -> halo re-reads become L2 hits; vmcnt(2) drain ~200cyc not
//      ~900 -> less barrier stall.
// Pipeline (u = t mod 9; t%3 == u%3 since 9%3==0; t in [0,54)):
//   top-bar(t): vmcnt(2|0) lgkmcnt(0) + s_barrier   t in [2,51)
//   stage(t):   slice t -> sIJ[t%3]                 t in [0,48)
//   C(t):       ws[(t+1)&1] (slice t-3) H-sums + D-ring   t in [3,51), emit t>=11
//   B(t):       sIJ[(t-2)%3] -> W-sums -> ws[t&1]   t in [2,50)
// ---------------------------------------------------------------------------
__global__ __launch_bounds__(256, 3) void ncc_fused(const float* __restrict__ I,
                                                    const float* __restrict__ J,
                                                    float* __restrict__ bsum) {
  __shared__ float4 sIJ[3][480];        // 23040 B [buf][ I 0..239 | J 240..479 ]
  __shared__ float4 ws4[2][RH][TWP];    // 25344 B W-sums f0-3, double-buffered
  __shared__ float  ws1[2][RH][TWP];    //  6336 B W-sums f4,   double-buffered
                                        // total 54720 B -> 2 blocks/CU

  const int tid = threadIdx.x;

  // XCD swizzle: consecutive lids (which share W/H halos) land on ONE XCD.
  // HW round-robins bid -> XCD (bid%8); lid groups of 60 = one (chunk,batch)
  // slab of 5x12 tiles per XCD. Bijective since 480 % 8 == 0.
  const int bid = blockIdx.x;                   // 0..479
  const int lid = (bid & 7) * 60 + (bid >> 3);
  const int w0 = (lid % 5) * TW;                // 5 W tiles
  const int h0 = ((lid / 5) % 12) * TH;         // 12 H tiles
  const int zz = lid / 60;                      // 0..7
  const int c0 = (zz & 3) * DC;                 // 4 chunks
  const int batch = zz >> 2;                    // 2

  const float* Ib = I + (size_t)batch * V_;
  const float* Jb = J + (size_t)batch * V_;
  const float* zp = zpad_g;

  // Staging chunks g0=tid, g1=tid+256 of 480. chunk g: arr=g/240, rem=g%240,
  // row r=rem/10 (h=h0-4+r), quad q=rem%10 (col=w0-4+4q, quad-aligned).
  const int g0 = tid, g1 = tid + 256;
  const int a0 = g0 / 240, rem0 = g0 % 240;
  const int r0 = rem0 / 10, q0 = rem0 % 10;
  const int h0g = h0 - 4 + r0, c0g = w0 - 4 + 4 * q0;
  const bool ok0 = ((unsigned)h0g < (unsigned)H_) && ((unsigned)c0g < (unsigned)W_);
  const float* gb0 = (a0 ? Jb : Ib) + (ok0 ? ((size_t)h0g * W_ + c0g) : 0);

  const int a1 = (g1 / 240) & 1, rem1 = g1 % 240;
  const int r1 = rem1 / 10, q1 = rem1 % 10;
  const int h1g = h0 - 4 + r1, c1g = w0 - 4 + 4 * q1;
  const bool okd1 = ((unsigned)h1g < (unsigned)H_) && ((unsigned)c1g < (unsigned)W_);
  const float* gb1 = (a1 ? Jb : Ib) + (okd1 ? ((size_t)h1g * W_ + c1g) : 0);

  // Wave-uniform LDS byte bases for the two DMA issues.
  const int wv  = tid >> 6;
  const int wb0 = wv * 1024;           // chunks [wv*64, wv*64+64)
  const int wb1 = 4096 + wv * 1024;    // chunks [256+wv*64, ...)

  // B mapping (tid < 192): wave w -> rows 8w+(tid&7), run (tid>>3)&7.
  // (row varies with LOW lane bits -> ws4-write bank starts spread.)
  const int br = ((tid >> 6) << 3) | (tid & 7);
  const int brun = (tid >> 3) & 7;
  const int bc = brun * 4;

  // C mapping: col tx, output rows hb, hb+1
  const int tx = tid & 31;
  const int hb = (tid >> 5) * 2;

  unsigned ring[5][9];
  float sum0[5], sum1[5];
#pragma unroll
  for (int f = 0; f < 5; ++f) {
    sum0[f] = 0.f; sum1[f] = 0.f;
#pragma unroll
    for (int k = 0; k < 9; ++k) ring[f][k] = 0u;
  }

  float local = 0.f;

#pragma unroll 1
  for (int tb = 0; tb < 54; tb += 9) {
#pragma unroll
    for (int u = 0; u < 9; ++u) {
      const int t = tb + u;          // 0..53; phases self-guard (51..53 idle)

      // ---- top-of-step barrier: drains slice t-2 (vmcnt(2): stage(t-1)
      //      stays in flight), makes B(t-1)'s ws writes visible, and protects
      //      sIJ[t%3] (read by B(t-1)) from stage(t)'s DMA. ----
      if (t >= 2 && t < DC + 11) {
        if (t < DC + 9) {
          asm volatile("s_waitcnt vmcnt(2) lgkmcnt(0)" ::: "memory");
        } else {
          asm volatile("s_waitcnt vmcnt(0) lgkmcnt(0)" ::: "memory");
        }
        __builtin_amdgcn_s_barrier();
      }

      // ---- stage: slice s = c0-4+t -> sIJ[t%3]; EVERY wave issues 2 DMAs ----
      if (t < DC + 8) {
        const int s = c0 - 4 + t;
        const bool sin = (unsigned)s < (unsigned)D_;
        const size_t so = sin ? (size_t)s * HW_ : 0;
        char* lbase = (char*)&sIJ[u % 3][0];   // t%3 == u%3 (tb multiple of 9)
        const float* A0 = (sin && ok0) ? (gb0 + so) : zp;
        GLD16(A0, lbase + wb0);
        if (g1 < 480) {                // lane-masked; still 1 issue per wave
          const float* A1 = (sin && okd1) ? (gb1 + so) : zp;
          GLD16(A1, lbase + wb1);
        }
      }

      // ---- C: H-dir 9-sums of ws[(t+1)&1] (= slice t-3) + bf16 D-ring ----
      if (t >= 3 && t < DC + 11) {
        const float4 (*W4r)[TWP] = ws4[(t + 1) & 1];
        const float  (*W1r)[TWP] = ws1[(t + 1) & 1];
        float v0 = 0.f, v1 = 0.f, v2 = 0.f, v3 = 0.f, v4 = 0.f;
        float4 k4; float k1v;
#pragma unroll
        for (int k = 0; k < 9; ++k) {
          const float4 a4 = W4r[hb + k][tx];
          const float  a1f = W1r[hb + k][tx];
          if (k == 0) { k4 = a4; k1v = a1f; }
          v0 += a4.x; v1 += a4.y; v2 += a4.z; v3 += a4.w; v4 += a1f;
        }
        const float4 t4 = W4r[hb + 9][tx];
        const float  t1 = W1r[hb + 9][tx];
        float hv0[5], hv1[5];
        hv0[0] = v0; hv0[1] = v1; hv0[2] = v2; hv0[3] = v3; hv0[4] = v4;
        hv1[0] = v0 + t4.x - k4.x;
        hv1[1] = v1 + t4.y - k4.y;
        hv1[2] = v2 + t4.z - k4.z;
        hv1[3] = v3 + t4.w - k4.w;
        hv1[4] = v4 + t1   - k1v;

#pragma unroll
        for (int f = 0; f < 5; ++f) {
          const float2 old = unpack_bf2(ring[f][u]);
          sum0[f] += hv0[f] - old.x;
          sum1[f] += hv1[f] - old.y;
          ring[f][u] = pack_bf2(hv0[f], hv1[f]);
        }

        if (t >= 11) {
          const float inv = 1.f / 729.f;
          const float cx0 = sum0[4] - sum0[0] * sum0[1] * inv;
          const float iv0 = sum0[2] - sum0[0] * sum0[0] * inv;
          const float jv0 = sum0[3] - sum0[1] * sum0[1] * inv;
          local += cx0 * cx0 * __builtin_amdgcn_rcpf(iv0 * jv0 + 1e-5f);
          const float cx1 = sum1[4] - sum1[0] * sum1[1] * inv;
          const float iv1 = sum1[2] - sum1[0] * sum1[0] * inv;
          const float jv1 = sum1[3] - sum1[1] * sum1[1] * inv;
          local += cx1 * cx1 * __builtin_amdgcn_rcpf(iv1 * jv1 + 1e-5f);
        }
      }

      // ---- B: W-dir 9-sums of slice t-2 from sIJ[(t-2)%3] -> ws[t&1] ----
      //      (same region as C: no barrier between them; pipes interleave)
      if (t >= 2 && t < DC + 10 && tid < 192) {
        const float4* SI = &sIJ[(u + 1) % 3][br * 10 + brun];  // (t-2)%3
        const float4* SJ = SI + 240;
        const float4 A0 = SI[0], A1 = SI[1], A2 = SI[2];
        const float4 B0 = SJ[0], B1 = SJ[1], B2 = SJ[2];
        const float ai[12] = {A0.x,A0.y,A0.z,A0.w, A1.x,A1.y,A1.z,A1.w,
                              A2.x,A2.y,A2.z,A2.w};
        const float aj[12] = {B0.x,B0.y,B0.z,B0.w, B1.x,B1.y,B1.z,B1.w,
                              B2.x,B2.y,B2.z,B2.w};
        float4* W4 = ws4[t & 1][br];
        float*  W1 = ws1[t & 1][br];
        float s0 = 0.f, s1 = 0.f, s2 = 0.f, s3 = 0.f, s4 = 0.f;
#pragma unroll
        for (int k = 0; k < 9; ++k) {
          const float a = ai[k], b = aj[k];
          s0 += a; s1 += b; s2 += a * a; s3 += b * b; s4 += a * b;
        }
        W4[bc] = make_float4(s0, s1, s2, s3);
        W1[bc] = s4;
#pragma unroll
        for (int m = 1; m < 4; ++m) {
          const float ea = ai[8 + m], eb = aj[8 + m];
          const float la = ai[m - 1], lb = aj[m - 1];
          s0 += ea - la;
          s1 += eb - lb;
          s2 += ea * ea - la * la;
          s3 += eb * eb - lb * lb;
          s4 += ea * eb - la * lb;
          W4[bc + m] = make_float4(s0, s1, s2, s3);
          W1[bc + m] = s4;
        }
      }
    }
  }

  // ---- block reduction (reuse ws4 space) -> per-block partial ----
  __syncthreads();   // C(50)'s ws reads consumed before the space is reused
  float* red = (float*)&ws4[0][0][0];
  red[tid] = local;
  __syncthreads();
  for (int s2 = 128; s2 > 0; s2 >>= 1) {
    if (tid < s2) red[tid] += red[tid + s2];
    __syncthreads();
  }
  if (tid == 0) bsum[bid] = red[0];
}

__global__ __launch_bounds__(256) void finalize_k(const float* __restrict__ bsum,
                                                  float* __restrict__ out) {
  __shared__ double red[256];
  double d = 0.0;
  for (int i = threadIdx.x; i < NBLOCKS; i += 256) d += (double)bsum[i];
  red[threadIdx.x] = d;
  __syncthreads();
  for (int s = 128; s > 0; s >>= 1) {
    if (threadIdx.x < s) red[threadIdx.x] += red[threadIdx.x + s];
    __syncthreads();
  }
  if (threadIdx.x == 0) out[0] = (float)(-red[0] / (double)NTOT);
}

extern "C" void kernel_launch(void* const* d_in, const int* in_sizes, int n_in,
                              void* d_out, int out_size, void* d_ws, size_t ws_size,
                              hipStream_t stream) {
  const float* I = (const float*)d_in[0];   // y_true
  const float* J = (const float*)d_in[1];   // y_pred
  float* out = (float*)d_out;
  float* bsum = (float*)d_ws;               // 480 floats

  ncc_fused<<<dim3(NBLOCKS), 256, 0, stream>>>(I, J, bsum);
  finalize_k<<<1, 256, 0, stream>>>(bsum, out);
}